// Round 20
// baseline (609.371 us; speedup 1.0000x reference)
//
#include <hip/hip_runtime.h>
#include <hip/hip_cooperative_groups.h>
#include <stdint.h>

namespace cg = cooperative_groups;

#define N_VOX   (1 << 19)
#define CIN     64
#define COUT    128
#define BIN_SHIFT 6
#define BINS    (1 << 17)          // lambda = 4/bin
#define OFF_BITS 7                 // intra-bin arrival offset
#define BPB     64                 // bins per k_mega block (~256 positions)
#define NBLK    (BINS / BPB)       // 2048 mega blocks
#define PCAP    384                // max positions per mega block
#define NSB     1024               // k_sort blocks (co-resident: 4/CU)
#define BINS_PER_SB (BINS / NSB)   // 128
#define EPSV    1e-5f

typedef float f32x4 __attribute__((ext_vector_type(4)));

static __device__ __forceinline__ void nt_store4(float* p, f32x4 v) {
    __builtin_nontemporal_store(v, (f32x4*)p);
}

// Established: d_out stores ~2.8 TB/s (destination wall, r15 differential
// probe); drain floor ~97us for 276 MB. r20: the 4-kernel sort chain fuses
// into ONE cooperative kernel (grid.sync replaces kernel boundaries and the
// decoupled-lookback machinery). Pipeline = k_sort + k_mega, 2 launches.
//
// ws ints: hist[BINS] | cursor[BINS] | bsum[NSB] | packed[N] | recs[2*N]

__global__ __launch_bounds__(256, 4) void k_sort(
    const int* __restrict__ idx, unsigned* __restrict__ packed,
    int* __restrict__ hist, int* __restrict__ cursor,
    int* __restrict__ bsum, uint2* __restrict__ recs) {
    cg::grid_group grid = cg::this_grid();
    __shared__ int a4[4];
    int tid = threadIdx.x, B = blockIdx.x;
    int lane = tid & 63, w = tid >> 6;
    int hbase = B * BINS_PER_SB;
    int gid = B * 256 + tid;

    // P1: clear hist stripe (128 ints/block)
    if (tid < BINS_PER_SB) hist[hbase + tid] = 0;
    grid.sync();

    // P2: histogram + packed (2 elems/thread)
    #pragma unroll
    for (int r = 0; r < 2; r++) {
        int e = gid + r * (NSB * 256);
        int4 v = *(const int4*)&idx[e * 4];
        int lin = ((v.x * 8 + v.y) * 512 + v.z) * 512 + v.w;
        int off = atomicAdd(&hist[lin >> BIN_SHIFT], 1);
        packed[e] = ((unsigned)lin << OFF_BITS) | (unsigned)off;
    }
    grid.sync();

    // P3a: block sums its 128 bins -> bsum[B]
    int hv = (tid < BINS_PER_SB) ? hist[hbase + tid] : 0;
    {
        int s = hv;
        #pragma unroll
        for (int off = 32; off > 0; off >>= 1) s += __shfl_xor(s, off);
        if (lane == 0) a4[w] = s;
        __syncthreads();
        if (tid == 0) bsum[B] = a4[0] + a4[1] + a4[2] + a4[3];
    }
    grid.sync();

    // P3b: block 0 exclusive-scans bsum[NSB] in place
    if (B == 0) {
        int4 v = *(const int4*)&bsum[tid * 4];
        int t2 = v.x + v.y + v.z;
        int t3 = t2 + v.w;
        int incl = t3;
        #pragma unroll
        for (int off = 1; off < 64; off <<= 1) {
            int u = __shfl_up(incl, off);
            if (lane >= off) incl += u;
        }
        __syncthreads();               // a4 reuse hazard
        if (lane == 63) a4[w] = incl;
        __syncthreads();
        int woff = (w > 0 ? a4[0] : 0) + (w > 1 ? a4[1] : 0) + (w > 2 ? a4[2] : 0);
        int excl = woff + incl - t3;
        int4 e4;
        e4.x = excl;
        e4.y = excl + v.x;
        e4.z = excl + v.x + v.y;
        e4.w = excl + t2;
        *(int4*)&bsum[tid * 4] = e4;
    }
    grid.sync();

    // P3c: per-block exclusive scan of its 128 bins + block prefix -> cursor
    {
        int incl = hv;
        #pragma unroll
        for (int off = 1; off < 64; off <<= 1) {
            int u = __shfl_up(incl, off);
            if (lane >= off) incl += u;
        }
        __syncthreads();               // a4 reuse hazard
        if (lane == 63) a4[w] = incl;
        __syncthreads();
        int woff = (w == 1) ? a4[0] : 0;   // bins live in waves 0,1 only
        int excl = woff + incl - hv;
        if (tid < BINS_PER_SB) cursor[hbase + tid] = bsum[B] + excl;
    }
    grid.sync();

    // P4: scatter sorted-position records (lin, origrow)
    #pragma unroll
    for (int r = 0; r < 2; r++) {
        int e = gid + r * (NSB * 256);
        unsigned p = packed[e];
        unsigned lin = p >> OFF_BITS;
        int pos = cursor[lin >> BIN_SHIFT] + (int)(p & ((1u << OFF_BITS) - 1u));
        recs[pos] = make_uint2(lin, (unsigned)e);
    }
}

// ---- fused fixup + GEMM + LN, wave-private single-pass dense output ----
__global__ __launch_bounds__(256) void k_mega(
    const float* __restrict__ feats, const float* __restrict__ weight,
    const float* __restrict__ gamma, const float* __restrict__ beta,
    const int* __restrict__ hist, const int* __restrict__ cursor,
    const uint2* __restrict__ recs, float* __restrict__ out) {
    __shared__ float featb[4][8][CIN];         // 8 KB (wave-private slices)
    __shared__ unsigned slin[PCAP];            // 1.5 KB
    __shared__ int sperm[PCAP];                // 1.5 KB
    __shared__ unsigned short wvpos[4][96];    // 0.75 KB (per-wave valid lists)

    int tid = threadIdx.x;
    int w = tid >> 6, lane = tid & 63;
    int B0 = blockIdx.x * BPB;
    int p0 = cursor[B0];
    int p1 = (B0 + BPB < BINS) ? cursor[B0 + BPB] : N_VOX;
    int npos = p1 - p0;                        // ~Poisson(256), < PCAP

    // Phase A1: coalesced load of records into LDS
    for (int lp = tid; lp < npos; lp += 256) {
        uint2 r = recs[p0 + lp];
        slin[lp] = r.x;
        sperm[lp] = (int)r.y;
    }
    __syncthreads();

    // Phase A2: 1 bin/thread (tid<64), stable fixup in LDS (key = lin<<19|j)
    int c = 0, ls = 0;
    if (tid < BPB) {
        c = hist[B0 + tid];
        ls = cursor[B0 + tid] - p0;
    }
    if (c >= 2) {
        for (int i = 1; i < c; i++) {
            unsigned lj = slin[ls + i];
            int pj = sperm[ls + i];
            unsigned long long kj = ((unsigned long long)lj << 19) | (unsigned)pj;
            int m = i - 1;
            while (m >= 0) {
                unsigned lm = slin[ls + m];
                int pm = sperm[ls + m];
                unsigned long long km = ((unsigned long long)lm << 19) | (unsigned)pm;
                if (km <= kj) break;
                slin[ls + m + 1] = lm;
                sperm[ls + m + 1] = pm;
                m--;
            }
            slin[ls + m + 1] = lj;
            sperm[ls + m + 1] = pj;
        }
    }
    __syncthreads();                           // fixup visible block-wide

    // Wave-private range [r0, r1)
    int Q = (npos + 3) >> 2;
    int r0 = w * Q;
    int r1 = min(npos, r0 + Q);
    int half = lane >> 5, l32 = lane & 31;
    float* oidx = out + (size_t)N_VOX * COUT;

    // build per-wave valid list (ballot scan, order-preserving)
    int wnv = 0;
    for (int base = r0; base < r1; base += 64) {
        int lp = base + lane;
        bool valid = (lp < r1) && ((slin[lp] & 0x201u) == 0u);
        unsigned long long bv = __ballot(valid);
        int rank = __builtin_popcountll(bv & ((1ull << lane) - 1ull));
        if (valid) wvpos[w][wnv + rank] = (unsigned short)lp;
        wnv += __builtin_popcountll(bv);
    }

    // new_idx for this wave's range: ascending, 16B/lane (issued early)
    for (int lp = r0 + lane; lp < r1; lp += 64) {
        unsigned lin = slin[lp];
        f32x4 ni;
        if ((lin & 0x201u) == 0u) {
            ni.x = (float)(lin >> 21);
            ni.y = (float)((lin >> 18) & 7u);
            ni.z = (float)(((lin >> 9) & 511u) >> 1);
            ni.w = (float)((lin & 511u) >> 1);
        } else {
            ni = (f32x4){-1.f, -1.f, -1.f, -1.f};
        }
        nt_store4(&oidx[(size_t)(p0 + lp) * 4], ni);
    }

    f32x4 z = {0.f, 0.f, 0.f, 0.f};
    if (wnv == 0) {                            // whole range invalid
        for (int lp = r0 + half; lp < r1; lp += 2)
            nt_store4(&out[(size_t)(p0 + lp) * COUT + l32 * 4], z);
        return;
    }

    const f32x4* Wg4 = (const f32x4*)weight;   // [64][32] of float4
    f32x4 gv = *(const f32x4*)&gamma[l32 * 4];
    f32x4 bvv = *(const f32x4*)&beta[l32 * 4];
    int wcur = r0;

    for (int mb = 0; mb < wnv; mb += 8) {
        // gather 8 valid rows into wave-private LDS slice
        #pragma unroll
        for (int i = 0; i < 8; i++) {
            int m = mb + i;
            int lp = wvpos[w][(m < wnv) ? m : 0];
            featb[w][i][lane] = feats[(size_t)sperm[lp] * CIN + lane];
        }

        f32x4 acc[4];
        #pragma unroll
        for (int i = 0; i < 4; i++) acc[i] = z;

        #pragma unroll 4
        for (int k0 = 0; k0 < CIN; k0 += 4) {
            f32x4 wv0 = Wg4[(k0 + 0) * 32 + l32];
            f32x4 wv1 = Wg4[(k0 + 1) * 32 + l32];
            f32x4 wv2 = Wg4[(k0 + 2) * 32 + l32];
            f32x4 wv3 = Wg4[(k0 + 3) * 32 + l32];
            #pragma unroll
            for (int ii = 0; ii < 4; ii++) {
                float4 f = *(float4*)&featb[w][2 * ii + half][k0];
                acc[ii] += f.x * wv0;
                acc[ii] += f.y * wv1;
                acc[ii] += f.z * wv2;
                acc[ii] += f.w * wv3;
            }
        }

        // LN + store valid rows of this batch (each half owns 4 rows)
        #pragma unroll
        for (int ii = 0; ii < 4; ii++) {
            int m = mb + 2 * ii + half;
            f32x4 a = acc[ii];
            float sm = a.x + a.y + a.z + a.w;
            float sq = a.x * a.x + a.y * a.y + a.z * a.z + a.w * a.w;
            #pragma unroll
            for (int off = 16; off > 0; off >>= 1) {   // reduce within 32-lane half
                sm += __shfl_xor(sm, off);
                sq += __shfl_xor(sq, off);
            }
            float mean = sm * (1.0f / COUT);
            float var  = fmaxf(sq * (1.0f / COUT) - mean * mean, 0.0f);
            float rstd = rsqrtf(var + EPSV);
            if (m < wnv) {
                int pos = p0 + wvpos[w][m];
                f32x4 o = (a - mean) * rstd * gv + bvv;
                nt_store4(&out[(size_t)pos * COUT + l32 * 4], o);
            }
        }

        // zeros for invalid rows in window [wcur, wnext), split by parity
        int wnext = (mb + 8 < wnv) ? (int)wvpos[w][mb + 8] : r1;
        for (int lp = wcur + half; lp < wnext; lp += 2) {
            if (slin[lp] & 0x201u)
                nt_store4(&out[(size_t)(p0 + lp) * COUT + l32 * 4], z);
        }
        wcur = wnext;
    }
}

extern "C" void kernel_launch(void* const* d_in, const int* in_sizes, int n_in,
                              void* d_out, int out_size, void* d_ws, size_t ws_size,
                              hipStream_t stream) {
    const float* feats  = (const float*)d_in[0];
    const int*   idx    = (const int*)d_in[1];
    const float* weight = (const float*)d_in[2];
    const float* gamma  = (const float*)d_in[3];
    const float* beta   = (const float*)d_in[4];
    float* out = (float*)d_out;

    int* ws = (int*)d_ws;
    int*      hist   = ws;                         // BINS
    int*      cursor = ws + BINS;                  // BINS
    int*      bsum   = ws + 2 * BINS;              // NSB
    unsigned* packed = (unsigned*)(ws + 2 * BINS + NSB);  // N
    uint2*    recs   = (uint2*)(packed + N_VOX);   // N x 8B

    void* args[] = { (void*)&idx, (void*)&packed, (void*)&hist,
                     (void*)&cursor, (void*)&bsum, (void*)&recs };
    hipLaunchCooperativeKernel((const void*)k_sort, dim3(NSB), dim3(256),
                               args, 0, stream);
    k_mega<<<NBLK, 256, 0, stream>>>(feats, weight, gamma, beta,
                                     hist, cursor, recs, out);
}